// Round 1
// baseline (1192.471 us; speedup 1.0000x reference)
//
#include <hip/hip_runtime.h>
#include <hip/hip_bf16.h>
#include <cstdint>

#define TB 256

typedef short short8 __attribute__((ext_vector_type(8)));
typedef float f32x4 __attribute__((ext_vector_type(4)));

constexpr int B_N = 4096, I_N = 128, J_N = 512, G_N = 300;
constexpr int K1 = I_N * G_N;            // 38400 (per-d K)
constexpr int BM = 128, BN = 128, BK = 32;
constexpr int SPLITS = 4;
constexpr int KS = 2 * K1 / SPLITS;      // 19200 per split (one d, 64 i-values)
constexpr int NSTEP = KS / BK;           // 600

__device__ __forceinline__ ushort f2bf(float f) {
    unsigned int u = __float_as_uint(f);
    unsigned int r = (u + 0x7FFFu + ((u >> 16) & 1u)) >> 16;
    return (ushort)r;
}

typedef __attribute__((address_space(3))) unsigned int lds_u32_t;
typedef __attribute__((address_space(1))) const unsigned int glb_u32_t;

// async global->LDS, 16B per lane; lds dest = wave-uniform base + lane*16
__device__ __forceinline__ void llds16(const void* g, void* l) {
    __builtin_amdgcn_global_load_lds(
        reinterpret_cast<glb_u32_t*>(reinterpret_cast<uintptr_t>(g)),
        reinterpret_cast<lds_u32_t*>((unsigned int)reinterpret_cast<uintptr_t>(l)),
        16, 0, 0);
}

// pass 0: fc fp32 -> bf16 (ushort) in ws. 8 elems/thread.
__global__ __launch_bounds__(TB) void fkan_cvt(const float* __restrict__ src,
                                               ushort* __restrict__ dst) {
    size_t idx = (size_t)blockIdx.x * TB + threadIdx.x;
    const float4* s4 = (const float4*)src + idx * 2;
    float4 v0 = s4[0], v1 = s4[1];
    short8 o;
    o[0] = (short)f2bf(v0.x); o[1] = (short)f2bf(v0.y);
    o[2] = (short)f2bf(v0.z); o[3] = (short)f2bf(v0.w);
    o[4] = (short)f2bf(v1.x); o[5] = (short)f2bf(v1.y);
    o[6] = (short)f2bf(v1.z); o[7] = (short)f2bf(v1.w);
    *(short8*)(dst + idx * 8) = o;
}

// Fused trig-feature GEMM. Split sp: d = sp>>1 (0=cos,1=sin), i in [(sp&1)*64, +64).
template <bool USE_WS>
__global__ __launch_bounds__(TB)
void fkan_gemm(const float* __restrict__ x,
               const float* __restrict__ fc32,
               const ushort* __restrict__ fcb,
               float* __restrict__ out) {
    __shared__ float xs[BM][65];                    // +1 pad: conflict-free
    __shared__ __align__(16) ushort At[4 * 128 * 8]; // [kg][m][8] 8KB
    __shared__ __align__(16) ushort Bt[4 * 128 * 8]; // [kg][n][8] 8KB

    const int tid = threadIdx.x;
    const int bm = blockIdx.x, bn = blockIdx.y, sp = blockIdx.z;
    const int d  = sp >> 1;
    const int ib = (sp & 1) << 6;       // i base for this split
    const int rbase = ib * G_N;         // 0 or 19200 (offset within d-block)

    // stage x[bm*128 .. +128][ib .. ib+64) into LDS
    for (int idx = tid; idx < BM * 64; idx += TB) {
        int row = idx >> 6, il = idx & 63;
        xs[row][il] = x[(size_t)(bm * BM + row) * I_N + ib + il];
    }

    f32x4 acc[4][4];
#pragma unroll
    for (int a = 0; a < 4; ++a)
#pragma unroll
        for (int b = 0; b < 4; ++b) acc[a][b] = (f32x4){0.f, 0.f, 0.f, 0.f};

    const int lane = tid & 63, wid = tid >> 6;
    const int wm = wid & 1, wn = wid >> 1;
    const int lhi = lane >> 4, llo = lane & 15;
    const int am = tid & 127, akg0 = tid >> 7;  // A-stage: rows, k-groups {akg0, akg0+2}

    const ushort* fbbase  = USE_WS ? fcb + ((size_t)d * J_N + bn * BN) * K1 + rbase : nullptr;
    const float*  f32base = !USE_WS ? fc32 + ((size_t)d * J_N + bn * BN) * K1 + rbase : nullptr;

    for (int step = 0; step < NSTEP; ++step) {
        __syncthreads();
        // ---- A tile: 4096 trig features, 16/thread ----
#pragma unroll
        for (int it = 0; it < 2; ++it) {
            const int kg = akg0 + it * 2;
            int r = rbase + step * BK + kg * 8;     // index within d-block
            int i = (int)((unsigned)r / 300u);
            int g = r - i * 300;
            float xv = xs[am][i - ib];
            float kf = (float)(g + 1);
            short8 av;
#pragma unroll
            for (int j = 0; j < 8; ++j) {
                float arg = xv * kf;
                float rev = arg * 0.15915494309189535f;   // to revolutions
                float fr  = rev - floorf(rev);            // exact range reduce
                float a2  = fr * 6.283185307179586f;
                float val;
                if (d) val = __sinf(a2); else val = __cosf(a2);
                av[j] = (short)f2bf(val);
                if (j < 7) {
                    ++g; kf += 1.0f;
                    if (g == 300) { g = 0; kf = 1.0f; ++i; xv = xs[am][i - ib]; }
                }
            }
            *(short8*)&At[kg * 1024 + am * 8] = av;
        }
        // ---- B tile ----
        if constexpr (USE_WS) {
#pragma unroll
            for (int q = 0; q < 2; ++q) {
                int s = wid * 128 + q * 64 + lane;   // linear slot 0..511
                int kg = s >> 7, n = s & 127;
                const ushort* gp = fbbase + (size_t)n * K1 + step * BK + kg * 8;
                char* lp = (char*)Bt + (wid * 128 + q * 64) * 16;  // wave-uniform
                llds16(gp, lp);
            }
        } else {
#pragma unroll
            for (int it = 0; it < 2; ++it) {
                int item = tid + it * TB;
                int n = item >> 2, grp = item & 3;
                const float* gp = f32base + (size_t)n * K1 + step * BK + grp * 8;
                float4 v0 = *(const float4*)gp;
                float4 v1 = *(const float4*)(gp + 4);
                short8 bv;
                bv[0] = (short)f2bf(v0.x); bv[1] = (short)f2bf(v0.y);
                bv[2] = (short)f2bf(v0.z); bv[3] = (short)f2bf(v0.w);
                bv[4] = (short)f2bf(v1.x); bv[5] = (short)f2bf(v1.y);
                bv[6] = (short)f2bf(v1.z); bv[7] = (short)f2bf(v1.w);
                *(short8*)&Bt[grp * 1024 + n * 8] = bv;
            }
        }
        __syncthreads();
        // ---- fragments + 16 MFMA ----
        short8 af[4], bf[4];
#pragma unroll
        for (int t = 0; t < 4; ++t) {
            af[t] = *(const short8*)&At[lhi * 1024 + (wm * 64 + t * 16 + llo) * 8];
            bf[t] = *(const short8*)&Bt[lhi * 1024 + (wn * 64 + t * 16 + llo) * 8];
        }
#pragma unroll
        for (int tm = 0; tm < 4; ++tm)
#pragma unroll
            for (int tn = 0; tn < 4; ++tn)
                acc[tm][tn] = __builtin_amdgcn_mfma_f32_16x16x32_bf16(
                    af[tm], bf[tn], acc[tm][tn], 0, 0, 0);
    }

    // ---- epilogue: atomic accumulate split-K partials ----
    const int row0 = bm * BM + wm * 64 + lhi * 4;
    const int col0 = bn * BN + wn * 64 + llo;
#pragma unroll
    for (int tm = 0; tm < 4; ++tm)
#pragma unroll
        for (int tn = 0; tn < 4; ++tn)
#pragma unroll
            for (int r = 0; r < 4; ++r)
                atomicAdd(&out[(size_t)(row0 + tm * 16 + r) * J_N + col0 + tn * 16],
                          acc[tm][tn][r]);
}

extern "C" void kernel_launch(void* const* d_in, const int* in_sizes, int n_in,
                              void* d_out, int out_size, void* d_ws, size_t ws_size,
                              hipStream_t stream) {
    const float* x  = (const float*)d_in[0];
    const float* fc = (const float*)d_in[1];
    float* out = (float*)d_out;

    hipMemsetAsync(d_out, 0, (size_t)out_size * sizeof(float), stream);

    const size_t need = (size_t)2 * J_N * K1 * sizeof(ushort);  // 78.6 MB
    dim3 grid(B_N / BM, J_N / BN, SPLITS);                      // 32 x 4 x 4 = 512 blocks

    if (ws_size >= need) {
        ushort* fcb = (ushort*)d_ws;
        int n8 = 2 * J_N * K1 / 8;  // 4,915,200 vec8 items
        fkan_cvt<<<n8 / TB, TB, 0, stream>>>(fc, fcb);
        fkan_gemm<true><<<grid, TB, 0, stream>>>(x, nullptr, fcb, out);
    } else {
        fkan_gemm<false><<<grid, TB, 0, stream>>>(x, fc, nullptr, out);
    }
}

// Round 2
// 834.567 us; speedup vs baseline: 1.4288x; 1.4288x over previous
//
#include <hip/hip_runtime.h>
#include <hip/hip_bf16.h>
#include <cstdint>

#define TB 256

typedef short short8 __attribute__((ext_vector_type(8)));
typedef float f32x4 __attribute__((ext_vector_type(4)));

constexpr int B_N = 4096, I_N = 128, J_N = 512, G_N = 300;
constexpr int K1 = I_N * G_N;            // 38400 per d
constexpr int BM = 128, BN = 128;
constexpr int SPLITS = 8;                // d(2) x i-chunk(4 x 32)
constexpr int IC = 32;                   // i per split
constexpr float INV2PI = 0.15915494309189535f;

__device__ __forceinline__ ushort f2bf(float f) {
    unsigned int u = __float_as_uint(f);
    return (ushort)((u + 0x7FFFu + ((u >> 16) & 1u)) >> 16);
}

__device__ __forceinline__ float fract_(float x) {
#if __has_builtin(__builtin_amdgcn_fractf)
    return __builtin_amdgcn_fractf(x);
#else
    return x - floorf(x);
#endif
}

// pack two floats -> packed bf16x2 (RNE)
__device__ __forceinline__ unsigned int pack_bf2(float a, float b) {
#if __has_builtin(__builtin_amdgcn_cvt_pk_bf16_f32)
    auto r = __builtin_amdgcn_cvt_pk_bf16_f32(a, b);
    unsigned int u;
    __builtin_memcpy(&u, &r, 4);
    return u;
#else
    return (unsigned int)f2bf(a) | ((unsigned int)f2bf(b) << 16);
#endif
}

typedef __attribute__((address_space(3))) unsigned int lds_u32_t;
typedef __attribute__((address_space(1))) const unsigned int glb_u32_t;

__device__ __forceinline__ void llds16(const void* g, void* l) {
    __builtin_amdgcn_global_load_lds(
        reinterpret_cast<glb_u32_t*>(reinterpret_cast<uintptr_t>(g)),
        reinterpret_cast<lds_u32_t*>((unsigned int)reinterpret_cast<uintptr_t>(l)),
        16, 0, 0);
}

// ---------------- pass 0: fc fp32 [d][j][i][g] -> bf16 [d][j][g][i] ----------------
constexpr int GH = 150;  // g half-tile per block
__global__ __launch_bounds__(TB) void fkan_tr(const float* __restrict__ src,
                                              ushort* __restrict__ dst) {
    __shared__ ushort tile[GH * 130];   // pitch 130: conflict-free scatter writes
    const int blk = blockIdx.x;         // 0..2047
    const int dj = blk >> 1;            // d*512 + j
    const int g0 = (blk & 1) * GH;
    const float* s = src + (size_t)dj * K1;                    // [i][g] fp32
    ushort* o = dst + (size_t)dj * K1 + (size_t)g0 * I_N;      // [g][i] bf16
    const int tid = threadIdx.x;

    for (int e = tid; e < I_N * GH; e += TB) {
        int i = e / GH;
        int gs = e - i * GH;
        tile[gs * 130 + i] = f2bf(s[(size_t)i * G_N + g0 + gs]);
    }
    __syncthreads();
    // write coalesced dwords: slot = gs*64 + i2  (i2 = pair of i)
    for (int sl = tid; sl < GH * 64; sl += TB) {
        int gs = sl >> 6, i2 = sl & 63;
        unsigned int v;
        __builtin_memcpy(&v, &tile[gs * 130 + i2 * 2], 4);
        ((unsigned int*)o)[(size_t)gs * 64 + i2] = v;
    }
}

// ---------------- fused trig GEMM, i-fastest k-order ----------------
// split sp: d = sp>>2, ib = (sp&3)*32.  step = g (0..299), BK=32 = the 32 i's.
__global__ __launch_bounds__(TB)
void fkan_gemm(const float* __restrict__ x,
               const ushort* __restrict__ fcb,
               float* __restrict__ out) {
    __shared__ __align__(16) ushort At[4 * 128 * 8];  // [kg][m][8]  8KB
    __shared__ __align__(16) ushort Bt[4 * 128 * 8];  // [kg][n][8]  8KB

    const int tid = threadIdx.x;
    const int bm = blockIdx.x, bn = blockIdx.y, sp = blockIdx.z;
    const int d = sp >> 2;
    const int ib = (sp & 3) * IC;
    const float qofs = d ? 0.0f : 0.25f;   // cos(t) = sin(t + 0.25 rev)

    const int lane = tid & 63, wid = tid >> 6;
    const int wm = wid & 1, wn = wid >> 1;
    const int lhi = lane >> 4, llo = lane & 15;
    const int am = tid & 127, half = tid >> 7;

    // hoist this thread's 16 x-values (pre-scaled to revolutions/k)
    float xv[16];
    {
        const float* xrow = x + (size_t)(bm * BM + am) * I_N + ib + half * 16;
#pragma unroll
        for (int j = 0; j < 16; ++j) xv[j] = xrow[j] * INV2PI;
    }

    f32x4 acc[4][4];
#pragma unroll
    for (int a = 0; a < 4; ++a)
#pragma unroll
        for (int b = 0; b < 4; ++b) acc[a][b] = (f32x4){0.f, 0.f, 0.f, 0.f};

    // fcb tile base: [d][j = bn*128 + n][g][i = ib + ...]
    const ushort* fbase = fcb + ((size_t)(d * J_N + bn * BN)) * K1 + ib;
    // per slot (kg, n), g: addr = fbase + n*K1 + g*I_N + kg*8

    for (int g = 0; g < G_N; ++g) {
        __syncthreads();
        // ---- B stage first (long latency, overlaps A trig) ----
#pragma unroll
        for (int q = 0; q < 2; ++q) {
            int s = wid * 128 + q * 64 + lane;
            int kg = s >> 7, n = s & 127;
            const ushort* gp = fbase + (size_t)n * K1 + (size_t)g * I_N + kg * 8;
            char* lp = (char*)Bt + (wid * 128 + q * 64) * 16;  // wave-uniform base
            llds16(gp, lp);
        }
        // ---- A stage: 16 trig elems/thread, uniform kf ----
        const float kf = (float)(g + 1);
        unsigned int av[8];
#pragma unroll
        for (int j = 0; j < 8; ++j) {
            float f0 = fract_(__builtin_fmaf(xv[2 * j], kf, qofs));
            float f1 = fract_(__builtin_fmaf(xv[2 * j + 1], kf, qofs));
            av[j] = pack_bf2(__builtin_amdgcn_sinf(f0), __builtin_amdgcn_sinf(f1));
        }
        {
            uint4 lo = {av[0], av[1], av[2], av[3]};
            uint4 hi = {av[4], av[5], av[6], av[7]};
            *(uint4*)&At[((half * 2 + 0) * 128 + am) * 8] = lo;
            *(uint4*)&At[((half * 2 + 1) * 128 + am) * 8] = hi;
        }
        __syncthreads();
        // ---- fragments + 16 MFMA ----
        short8 af[4], bf[4];
#pragma unroll
        for (int t = 0; t < 4; ++t) {
            af[t] = *(const short8*)&At[(lhi * 128 + wm * 64 + t * 16 + llo) * 8];
            bf[t] = *(const short8*)&Bt[(lhi * 128 + wn * 64 + t * 16 + llo) * 8];
        }
#pragma unroll
        for (int tm = 0; tm < 4; ++tm)
#pragma unroll
            for (int tn = 0; tn < 4; ++tn)
                acc[tm][tn] = __builtin_amdgcn_mfma_f32_16x16x32_bf16(
                    af[tm], bf[tn], acc[tm][tn], 0, 0, 0);
    }

    const int row0 = bm * BM + wm * 64 + lhi * 4;
    const int col0 = bn * BN + wn * 64 + llo;
#pragma unroll
    for (int tm = 0; tm < 4; ++tm)
#pragma unroll
        for (int tn = 0; tn < 4; ++tn)
#pragma unroll
            for (int r = 0; r < 4; ++r)
                atomicAdd(&out[(size_t)(row0 + tm * 16 + r) * J_N + col0 + tn * 16],
                          acc[tm][tn][r]);
}

// ---------------- fallback (ws too small): Round-1 fp32-direct kernel ----------------
constexpr int SPL_FB = 4;
constexpr int KS_FB = 2 * K1 / SPL_FB;
constexpr int NSTEP_FB = KS_FB / 32;

__global__ __launch_bounds__(TB)
void fkan_gemm_fb(const float* __restrict__ x,
                  const float* __restrict__ fc32,
                  float* __restrict__ out) {
    __shared__ float xs[BM][65];
    __shared__ __align__(16) ushort At[4 * 128 * 8];
    __shared__ __align__(16) ushort Bt[4 * 128 * 8];

    const int tid = threadIdx.x;
    const int bm = blockIdx.x, bn = blockIdx.y, sp = blockIdx.z;
    const int d = sp >> 1;
    const int ib = (sp & 1) << 6;
    const int rbase = ib * G_N;

    for (int idx = tid; idx < BM * 64; idx += TB) {
        int row = idx >> 6, il = idx & 63;
        xs[row][il] = x[(size_t)(bm * BM + row) * I_N + ib + il];
    }

    f32x4 acc[4][4];
#pragma unroll
    for (int a = 0; a < 4; ++a)
#pragma unroll
        for (int b = 0; b < 4; ++b) acc[a][b] = (f32x4){0.f, 0.f, 0.f, 0.f};

    const int lane = tid & 63, wid = tid >> 6;
    const int wm = wid & 1, wn = wid >> 1;
    const int lhi = lane >> 4, llo = lane & 15;
    const int am = tid & 127, akg0 = tid >> 7;

    const float* f32base = fc32 + ((size_t)d * J_N + bn * BN) * K1 + rbase;

    for (int step = 0; step < NSTEP_FB; ++step) {
        __syncthreads();
#pragma unroll
        for (int it = 0; it < 2; ++it) {
            const int kg = akg0 + it * 2;
            int r = rbase + step * 32 + kg * 8;
            int i = (int)((unsigned)r / 300u);
            int g = r - i * 300;
            float xxv = xs[am][i - ib];
            float kkf = (float)(g + 1);
            short8 avv;
#pragma unroll
            for (int j = 0; j < 8; ++j) {
                float rev = xxv * kkf * INV2PI;
                float fr = fract_(rev) + (d ? 0.0f : 0.25f);
                avv[j] = (short)f2bf(__builtin_amdgcn_sinf(fract_(fr)));
                if (j < 7) {
                    ++g; kkf += 1.0f;
                    if (g == 300) { g = 0; kkf = 1.0f; ++i; xxv = xs[am][i - ib]; }
                }
            }
            *(short8*)&At[(kg * 128 + am) * 8] = avv;
        }
#pragma unroll
        for (int it = 0; it < 2; ++it) {
            int item = tid + it * TB;
            int n = item >> 2, grp = item & 3;
            const float* gp = f32base + (size_t)n * K1 + step * 32 + grp * 8;
            float4 v0 = *(const float4*)gp;
            float4 v1 = *(const float4*)(gp + 4);
            short8 bv;
            bv[0] = (short)f2bf(v0.x); bv[1] = (short)f2bf(v0.y);
            bv[2] = (short)f2bf(v0.z); bv[3] = (short)f2bf(v0.w);
            bv[4] = (short)f2bf(v1.x); bv[5] = (short)f2bf(v1.y);
            bv[6] = (short)f2bf(v1.z); bv[7] = (short)f2bf(v1.w);
            *(short8*)&Bt[(grp * 128 + n) * 8] = bv;
        }
        __syncthreads();
        short8 af[4], bf[4];
#pragma unroll
        for (int t = 0; t < 4; ++t) {
            af[t] = *(const short8*)&At[(lhi * 128 + wm * 64 + t * 16 + llo) * 8];
            bf[t] = *(const short8*)&Bt[(lhi * 128 + wn * 64 + t * 16 + llo) * 8];
        }
#pragma unroll
        for (int tm = 0; tm < 4; ++tm)
#pragma unroll
            for (int tn = 0; tn < 4; ++tn)
                acc[tm][tn] = __builtin_amdgcn_mfma_f32_16x16x32_bf16(
                    af[tm], bf[tn], acc[tm][tn], 0, 0, 0);
    }

    const int row0 = bm * BM + wm * 64 + lhi * 4;
    const int col0 = bn * BN + wn * 64 + llo;
#pragma unroll
    for (int tm = 0; tm < 4; ++tm)
#pragma unroll
        for (int tn = 0; tn < 4; ++tn)
#pragma unroll
            for (int r = 0; r < 4; ++r)
                atomicAdd(&out[(size_t)(row0 + tm * 16 + r) * J_N + col0 + tn * 16],
                          acc[tm][tn][r]);
}

extern "C" void kernel_launch(void* const* d_in, const int* in_sizes, int n_in,
                              void* d_out, int out_size, void* d_ws, size_t ws_size,
                              hipStream_t stream) {
    const float* x = (const float*)d_in[0];
    const float* fc = (const float*)d_in[1];
    float* out = (float*)d_out;

    hipMemsetAsync(d_out, 0, (size_t)out_size * sizeof(float), stream);

    const size_t need = (size_t)2 * J_N * K1 * sizeof(ushort);  // 78.6 MB

    if (ws_size >= need) {
        ushort* fcb = (ushort*)d_ws;
        fkan_tr<<<2 * J_N * 2, TB, 0, stream>>>(fc, fcb);          // 2048 blocks
        dim3 grid(B_N / BM, J_N / BN, SPLITS);                     // 32 x 4 x 8
        fkan_gemm<<<grid, TB, 0, stream>>>(x, fcb, out);
    } else {
        dim3 grid(B_N / BM, J_N / BN, SPL_FB);
        fkan_gemm_fb<<<grid, TB, 0, stream>>>(x, fc, out);
    }
}

// Round 3
// 756.246 us; speedup vs baseline: 1.5768x; 1.1036x over previous
//
#include <hip/hip_runtime.h>
#include <hip/hip_bf16.h>
#include <cstdint>

#define TB 256

typedef short short8 __attribute__((ext_vector_type(8)));
typedef float f32x4 __attribute__((ext_vector_type(4)));

constexpr int B_N = 4096, I_N = 128, J_N = 512, G_N = 300;
constexpr int K1 = I_N * G_N;            // 38400 per d
constexpr int BM = 128, BN = 256;
constexpr int NSP = 8;                   // 8 i-chunks of 16
constexpr int IC = 16;
constexpr float INV2PI = 0.15915494309189535f;

__device__ __forceinline__ ushort f2bf(float f) {
    unsigned int u = __float_as_uint(f);
    return (ushort)((u + 0x7FFFu + ((u >> 16) & 1u)) >> 16);
}

__device__ __forceinline__ float fract_(float x) {
#if __has_builtin(__builtin_amdgcn_fractf)
    return __builtin_amdgcn_fractf(x);
#else
    return x - floorf(x);
#endif
}

__device__ __forceinline__ unsigned int pack_bf2(float a, float b) {
#if __has_builtin(__builtin_amdgcn_cvt_pk_bf16_f32)
    auto r = __builtin_amdgcn_cvt_pk_bf16_f32(a, b);
    unsigned int u;
    __builtin_memcpy(&u, &r, 4);
    return u;
#else
    return (unsigned int)f2bf(a) | ((unsigned int)f2bf(b) << 16);
#endif
}

typedef __attribute__((address_space(3))) unsigned int lds_u32_t;
typedef __attribute__((address_space(1))) const unsigned int glb_u32_t;

__device__ __forceinline__ void llds16(const void* g, void* l) {
    __builtin_amdgcn_global_load_lds(
        reinterpret_cast<glb_u32_t*>(reinterpret_cast<uintptr_t>(g)),
        reinterpret_cast<lds_u32_t*>((unsigned int)reinterpret_cast<uintptr_t>(l)),
        16, 0, 0);
}

// ---------------- pass 0: fc fp32 [d][j][i][g] -> bf16 [d][j][g][i] ----------------
constexpr int GH = 150;
__global__ __launch_bounds__(TB) void fkan_tr(const float* __restrict__ src,
                                              ushort* __restrict__ dst) {
    __shared__ ushort tile[GH * 130];
    const int blk = blockIdx.x;         // 0..2047
    const int dj = blk >> 1;
    const int g0 = (blk & 1) * GH;
    const float* s = src + (size_t)dj * K1;
    ushort* o = dst + (size_t)dj * K1 + (size_t)g0 * I_N;
    const int tid = threadIdx.x;

    for (int e = tid; e < I_N * GH; e += TB) {
        int i = e / GH;
        int gs = e - i * GH;
        tile[gs * 130 + i] = f2bf(s[(size_t)i * G_N + g0 + gs]);
    }
    __syncthreads();
    for (int sl = tid; sl < GH * 64; sl += TB) {
        int gs = sl >> 6, i2 = sl & 63;
        unsigned int v;
        __builtin_memcpy(&v, &tile[gs * 130 + i2 * 2], 4);
        ((unsigned int*)o)[(size_t)gs * 64 + i2] = v;
    }
}

// ---------------- fused trig GEMM: rotation recurrence, both d per block ----------------
// split sp: i in [sp*16, sp*16+16).  Per g-step BK=32:
//   kg0: cos i0..7   kg1: cos i8..15   kg2: sin i0..7   kg3: sin i8..15
__global__ __launch_bounds__(TB, 2)
void fkan_gemm(const float* __restrict__ x,
               const ushort* __restrict__ fcb,
               float* __restrict__ out) {
    __shared__ __align__(16) ushort At[4 * 128 * 8];  // [kg][m][8]   8KB
    __shared__ __align__(16) ushort Bt[4 * 256 * 8];  // [kg][n][8]  16KB

    const int tid = threadIdx.x;
    const int bm = blockIdx.x, bn = blockIdx.y, sp = blockIdx.z;

    const int lane = tid & 63, wid = tid >> 6;
    const int wm = wid & 1, wn = wid >> 1;
    const int lhi = lane >> 4, llo = lane & 15;
    const int m = tid & 127, half = tid >> 7;

    // ---- init rotation state: s,c = sin(x),cos(x); rot consts = same ----
    float sv[8], cv[8], s0[8], c0[8];
    {
        const float* xr = x + ((size_t)(bm * BM + m)) * I_N + sp * IC + half * 8;
        float4 xa = *(const float4*)xr;
        float4 xb = *(const float4*)(xr + 4);
        float xv[8] = {xa.x, xa.y, xa.z, xa.w, xb.x, xb.y, xb.z, xb.w};
#pragma unroll
        for (int j = 0; j < 8; ++j) {
            float r = fract_(xv[j] * INV2PI);
            s0[j] = __builtin_amdgcn_sinf(r);
            c0[j] = __builtin_amdgcn_cosf(r);
            sv[j] = s0[j];
            cv[j] = c0[j];
        }
    }

    // ---- B stage pointers: wave w handles kg=w ----
    // slot (kg=w, n = q*64+lane): fcb[d][bn*256+n][g][sp*16 + ihalf*8 ..+8]
    const int bd = wid >> 1, bih = wid & 1;
    const ushort* bp[4];
    char* ldst[4];
#pragma unroll
    for (int q = 0; q < 4; ++q) {
        int n = q * 64 + lane;
        bp[q] = fcb + ((size_t)(bd * J_N + bn * BN + n)) * K1 + sp * IC + bih * 8;
        ldst[q] = (char*)Bt + (size_t)(wid * 256 + q * 64) * 16;
    }

    // A store addresses (fixed per thread)
    ushort* awc = &At[(half * 128 + m) * 8];          // kg = half       (cos)
    ushort* aws = &At[((2 + half) * 128 + m) * 8];    // kg = 2 + half   (sin)

    f32x4 acc[4][8];
#pragma unroll
    for (int a = 0; a < 4; ++a)
#pragma unroll
        for (int b = 0; b < 8; ++b) acc[a][b] = (f32x4){0.f, 0.f, 0.f, 0.f};

    for (int g = 0; g < G_N; ++g) {
        __syncthreads();
        // ---- B async stage (4 x 16B per thread) ----
#pragma unroll
        for (int q = 0; q < 4; ++q) {
            llds16(bp[q], ldst[q]);
            bp[q] += I_N;   // next g
        }
        // ---- A: store current state (k = g+1) as bf16 ----
        {
            uint4 vc = {pack_bf2(cv[0], cv[1]), pack_bf2(cv[2], cv[3]),
                        pack_bf2(cv[4], cv[5]), pack_bf2(cv[6], cv[7])};
            *(uint4*)awc = vc;
            uint4 vs = {pack_bf2(sv[0], sv[1]), pack_bf2(sv[2], sv[3]),
                        pack_bf2(sv[4], sv[5]), pack_bf2(sv[6], sv[7])};
            *(uint4*)aws = vs;
        }
        // ---- rotate state by x ----
#pragma unroll
        for (int j = 0; j < 8; ++j) {
            float t = __builtin_fmaf(sv[j], c0[j], cv[j] * s0[j]);
            cv[j] = __builtin_fmaf(cv[j], c0[j], -(sv[j] * s0[j]));
            sv[j] = t;
        }
        __syncthreads();
        // ---- fragments + 32 MFMA ----
        short8 af[4], bf[8];
#pragma unroll
        for (int t = 0; t < 4; ++t)
            af[t] = *(const short8*)&At[(lhi * 128 + wm * 64 + t * 16 + llo) * 8];
#pragma unroll
        for (int t = 0; t < 8; ++t)
            bf[t] = *(const short8*)&Bt[(lhi * 256 + wn * 128 + t * 16 + llo) * 8];
#pragma unroll
        for (int tm = 0; tm < 4; ++tm)
#pragma unroll
            for (int tn = 0; tn < 8; ++tn)
                acc[tm][tn] = __builtin_amdgcn_mfma_f32_16x16x32_bf16(
                    af[tm], bf[tn], acc[tm][tn], 0, 0, 0);
    }

    const int row0 = bm * BM + wm * 64 + lhi * 4;
    const int col0 = bn * BN + wn * 128 + llo;
#pragma unroll
    for (int tm = 0; tm < 4; ++tm)
#pragma unroll
        for (int tn = 0; tn < 8; ++tn)
#pragma unroll
            for (int r = 0; r < 4; ++r)
                atomicAdd(&out[(size_t)(row0 + tm * 16 + r) * J_N + col0 + tn * 16],
                          acc[tm][tn][r]);
}

// ---------------- fallback (ws too small): fp32-direct ----------------
constexpr int SPL_FB = 4;
constexpr int KS_FB = 2 * K1 / SPL_FB;
constexpr int NSTEP_FB = KS_FB / 32;

__global__ __launch_bounds__(TB)
void fkan_gemm_fb(const float* __restrict__ x,
                  const float* __restrict__ fc32,
                  float* __restrict__ out) {
    __shared__ float xs[BM][65];
    __shared__ __align__(16) ushort At[4 * 128 * 8];
    __shared__ __align__(16) ushort Bt[4 * 128 * 8];

    const int tid = threadIdx.x;
    const int bm = blockIdx.x, bn = blockIdx.y, sp = blockIdx.z;
    const int d = sp >> 1;
    const int ib = (sp & 1) << 6;
    const int rbase = ib * G_N;

    for (int idx = tid; idx < BM * 64; idx += TB) {
        int row = idx >> 6, il = idx & 63;
        xs[row][il] = x[(size_t)(bm * BM + row) * I_N + ib + il];
    }

    f32x4 acc[4][4];
#pragma unroll
    for (int a = 0; a < 4; ++a)
#pragma unroll
        for (int b = 0; b < 4; ++b) acc[a][b] = (f32x4){0.f, 0.f, 0.f, 0.f};

    const int lane = tid & 63, wid = tid >> 6;
    const int wm = wid & 1, wn = wid >> 1;
    const int lhi = lane >> 4, llo = lane & 15;
    const int am = tid & 127, akg0 = tid >> 7;

    const float* f32base = fc32 + ((size_t)d * J_N + bn * 128) * K1 + rbase;

    for (int step = 0; step < NSTEP_FB; ++step) {
        __syncthreads();
#pragma unroll
        for (int it = 0; it < 2; ++it) {
            const int kg = akg0 + it * 2;
            int r = rbase + step * 32 + kg * 8;
            int i = (int)((unsigned)r / 300u);
            int g = r - i * 300;
            float xxv = xs[am][i - ib];
            float kkf = (float)(g + 1);
            short8 avv;
#pragma unroll
            for (int j = 0; j < 8; ++j) {
                float rev = xxv * kkf * INV2PI;
                float fr = fract_(rev) + (d ? 0.0f : 0.25f);
                avv[j] = (short)f2bf(__builtin_amdgcn_sinf(fract_(fr)));
                if (j < 7) {
                    ++g; kkf += 1.0f;
                    if (g == 300) { g = 0; kkf = 1.0f; ++i; xxv = xs[am][i - ib]; }
                }
            }
            *(short8*)&At[(kg * 128 + am) * 8] = avv;
        }
#pragma unroll
        for (int it = 0; it < 2; ++it) {
            int item = tid + it * TB;
            int n = item >> 2, grp = item & 3;
            const float* gp = f32base + (size_t)n * K1 + step * 32 + grp * 8;
            float4 v0 = *(const float4*)gp;
            float4 v1 = *(const float4*)(gp + 4);
            short8 bv;
            bv[0] = (short)f2bf(v0.x); bv[1] = (short)f2bf(v0.y);
            bv[2] = (short)f2bf(v0.z); bv[3] = (short)f2bf(v0.w);
            bv[4] = (short)f2bf(v1.x); bv[5] = (short)f2bf(v1.y);
            bv[6] = (short)f2bf(v1.z); bv[7] = (short)f2bf(v1.w);
            *(short8*)&Bt[(grp * 128 + n) * 8] = bv;
        }
        __syncthreads();
        short8 af[4], bf[4];
#pragma unroll
        for (int t = 0; t < 4; ++t) {
            af[t] = *(const short8*)&At[(lhi * 128 + wm * 64 + t * 16 + llo) * 8];
            bf[t] = *(const short8*)&Bt[(lhi * 128 + wn * 64 + t * 16 + llo) * 8];
        }
#pragma unroll
        for (int tm = 0; tm < 4; ++tm)
#pragma unroll
            for (int tn = 0; tn < 4; ++tn)
                acc[tm][tn] = __builtin_amdgcn_mfma_f32_16x16x32_bf16(
                    af[tm], bf[tn], acc[tm][tn], 0, 0, 0);
    }

    const int row0 = bm * BM + wm * 64 + lhi * 4;
    const int col0 = bn * 128 + wn * 64 + llo;
#pragma unroll
    for (int tm = 0; tm < 4; ++tm)
#pragma unroll
        for (int tn = 0; tn < 4; ++tn)
#pragma unroll
            for (int r = 0; r < 4; ++r)
                atomicAdd(&out[(size_t)(row0 + tm * 16 + r) * J_N + col0 + tn * 16],
                          acc[tm][tn][r]);
}

extern "C" void kernel_launch(void* const* d_in, const int* in_sizes, int n_in,
                              void* d_out, int out_size, void* d_ws, size_t ws_size,
                              hipStream_t stream) {
    const float* x = (const float*)d_in[0];
    const float* fc = (const float*)d_in[1];
    float* out = (float*)d_out;

    hipMemsetAsync(d_out, 0, (size_t)out_size * sizeof(float), stream);

    const size_t need = (size_t)2 * J_N * K1 * sizeof(ushort);  // 78.6 MB

    if (ws_size >= need) {
        ushort* fcb = (ushort*)d_ws;
        fkan_tr<<<2 * J_N * 2, TB, 0, stream>>>(fc, fcb);
        dim3 grid(B_N / BM, J_N / BN, NSP);                      // 32 x 2 x 8 = 512
        fkan_gemm<<<grid, TB, 0, stream>>>(x, fcb, out);
    } else {
        dim3 grid(B_N / BM, J_N / 128, SPL_FB);
        fkan_gemm_fb<<<grid, TB, 0, stream>>>(x, fc, out);
    }
}

// Round 4
// 697.650 us; speedup vs baseline: 1.7093x; 1.0840x over previous
//
#include <hip/hip_runtime.h>
#include <hip/hip_bf16.h>
#include <cstdint>

#define TB 256

typedef short short8 __attribute__((ext_vector_type(8)));
typedef float f32x4 __attribute__((ext_vector_type(4)));

constexpr int B_N = 4096, I_N = 128, J_N = 512, G_N = 300;
constexpr int K1 = I_N * G_N;            // 38400 per d
constexpr int BM = 128, BN = 256;
constexpr int NSP = 8;                   // 8 i-chunks of 16
constexpr int IC = 16;
constexpr float INV2PI = 0.15915494309189535f;

// fcb2 layout: [sp][g][kg][j][8e] bf16, kg = d*2 + ih, i = sp*16 + ih*8 + e
constexpr int GSTRIDE = 4 * 512 * 8;              // ushorts per g = 16384
constexpr size_t SPSTRIDE = (size_t)G_N * GSTRIDE;  // per sp

__device__ __forceinline__ ushort f2bf(float f) {
    unsigned int u = __float_as_uint(f);
    return (ushort)((u + 0x7FFFu + ((u >> 16) & 1u)) >> 16);
}

__device__ __forceinline__ float fract_(float x) {
#if __has_builtin(__builtin_amdgcn_fractf)
    return __builtin_amdgcn_fractf(x);
#else
    return x - floorf(x);
#endif
}

__device__ __forceinline__ unsigned int pack_bf2(float a, float b) {
#if __has_builtin(__builtin_amdgcn_cvt_pk_bf16_f32)
    auto r = __builtin_amdgcn_cvt_pk_bf16_f32(a, b);
    unsigned int u;
    __builtin_memcpy(&u, &r, 4);
    return u;
#else
    return (unsigned int)f2bf(a) | ((unsigned int)f2bf(b) << 16);
#endif
}

typedef __attribute__((address_space(3))) unsigned int lds_u32_t;
typedef __attribute__((address_space(1))) const unsigned int glb_u32_t;

__device__ __forceinline__ void llds16(const void* g, void* l) {
    __builtin_amdgcn_global_load_lds(
        reinterpret_cast<glb_u32_t*>(reinterpret_cast<uintptr_t>(g)),
        reinterpret_cast<lds_u32_t*>((unsigned int)reinterpret_cast<uintptr_t>(l)),
        16, 0, 0);
}

// ---------------- pass 0: fc f32 [d][j][i][g] -> fcb2 bf16 [sp][g][kg][j][8] ----------------
// block bx = gc*256 + djc*8 + sp : gc<5 (60 g), djc<32 (32 dj rows), sp<8 (16 i)
constexpr int TGC = 60;
__global__ __launch_bounds__(TB) void fkan_tr(const float* __restrict__ src,
                                              ushort* __restrict__ dst) {
    __shared__ __align__(16) ushort L[TGC * 2 * 32 * 8];   // [gl][ihl][jl][e] 60KB
    const int bx = blockIdx.x;
    const int sp = bx & 7, djc = (bx >> 3) & 31, gc = bx >> 8;
    const int dj0 = djc * 32;
    const int d = dj0 >> 9;
    const int j0 = dj0 & 511;
    const int g0 = gc * TGC;
    const int tid = threadIdx.x;
    const int djl = tid >> 3, i2 = tid & 7;
    const int iA = sp * 16 + i2 * 2;                   // covers i = iA, iA+1
    const size_t rowA = ((size_t)(dj0 + djl) * 128 + iA) * 300;
    const int ihl = i2 >> 2;
    const int eA = (i2 & 3) * 2;

#pragma unroll 3
    for (int gq = 0; gq < 15; ++gq) {
        const int gg = g0 + gq * 4;
        float4 va = *(const float4*)(src + rowA + gg);          // i = iA,   4 g
        float4 vb = *(const float4*)(src + rowA + 300 + gg);    // i = iA+1, 4 g
        float a[4] = {va.x, va.y, va.z, va.w};
        float b[4] = {vb.x, vb.y, vb.z, vb.w};
#pragma unroll
        for (int t = 0; t < 4; ++t) {
            int gl = gq * 4 + t;
            unsigned int w = (unsigned int)f2bf(a[t]) | ((unsigned int)f2bf(b[t]) << 16);
            *(unsigned int*)&L[(((gl * 2 + ihl) * 32 + djl) * 8 + eA)] = w;
        }
    }
    __syncthreads();
    // write out: 3840 uint4 slots, contiguous 512B runs per (g, ihl)
    const uint4* Lv = (const uint4*)L;
#pragma unroll 3
    for (int it = 0; it < 15; ++it) {
        int s = it * 256 + tid;
        int gl = s >> 6, r = s & 63;
        int ih = r >> 5, jl = r & 31;
        size_t d16 = ((size_t)(sp * G_N + g0 + gl) * 4 + d * 2 + ih) * 512 + j0 + jl;
        ((uint4*)dst)[d16] = Lv[s];
    }
}

// ---------------- fused trig GEMM: rotation recurrence, single-barrier dbuf pipeline ----------------
// split sp: i in [sp*16, +16). Per g-step BK=32: kg = d*2+ih (cos i0-7, cos i8-15, sin i0-7, sin i8-15)
__global__ __launch_bounds__(TB, 2)
void fkan_gemm(const float* __restrict__ x,
               const ushort* __restrict__ fcb,
               float* __restrict__ out) {
    __shared__ __align__(16) ushort At[2 * 4 * 128 * 8];  // 16KB  [buf][kg][m][8]
    __shared__ __align__(16) ushort Bt[2 * 4 * 256 * 8];  // 32KB  [buf][kg][n][8]

    const int tid = threadIdx.x;
    const int bm = blockIdx.x, bn = blockIdx.y, sp = blockIdx.z;
    const int lane = tid & 63, wid = tid >> 6;
    const int wm = wid & 1, wn = wid >> 1;
    const int lhi = lane >> 4, llo = lane & 15;
    const int m = tid & 127, half = tid >> 7;

    // ---- init rotation state: k=1 ----
    float sv[8], cv[8], s0[8], c0[8];
    {
        const float* xr = x + ((size_t)(bm * BM + m)) * I_N + sp * IC + half * 8;
        float4 xa = *(const float4*)xr;
        float4 xb = *(const float4*)(xr + 4);
        float xv[8] = {xa.x, xa.y, xa.z, xa.w, xb.x, xb.y, xb.z, xb.w};
#pragma unroll
        for (int j = 0; j < 8; ++j) {
            float r = fract_(xv[j] * INV2PI);
            s0[j] = __builtin_amdgcn_sinf(r);
            c0[j] = __builtin_amdgcn_cosf(r);
            sv[j] = s0[j];
            cv[j] = c0[j];
        }
    }

    // ---- B pointers: wave w stages kg=w, 4 lane-linear 1KB chunks ----
    const ushort* bp[4];
#pragma unroll
    for (int q = 0; q < 4; ++q)
        bp[q] = fcb + (size_t)sp * SPSTRIDE
              + ((size_t)wid * 512 + bn * BN + q * 64 + lane) * 8;

    // A store addrs per buffer
    ushort* awc[2];
    ushort* aws[2];
    awc[0] = &At[(half * 128 + m) * 8];        awc[1] = awc[0] + 4096;
    aws[0] = &At[((2 + half) * 128 + m) * 8];  aws[1] = aws[0] + 4096;

    f32x4 acc[4][8];
#pragma unroll
    for (int a = 0; a < 4; ++a)
#pragma unroll
        for (int b = 0; b < 8; ++b) acc[a][b] = (f32x4){0.f, 0.f, 0.f, 0.f};

    // ---- prologue: A(g=0) into buf0 (state k=1), rotate; B(0) -> buf0 ----
    {
        uint4 vc = {pack_bf2(cv[0], cv[1]), pack_bf2(cv[2], cv[3]),
                    pack_bf2(cv[4], cv[5]), pack_bf2(cv[6], cv[7])};
        *(uint4*)awc[0] = vc;
        uint4 vs = {pack_bf2(sv[0], sv[1]), pack_bf2(sv[2], sv[3]),
                    pack_bf2(sv[4], sv[5]), pack_bf2(sv[6], sv[7])};
        *(uint4*)aws[0] = vs;
#pragma unroll
        for (int j = 0; j < 8; ++j) {
            float t = __builtin_fmaf(sv[j], c0[j], cv[j] * s0[j]);
            cv[j] = __builtin_fmaf(cv[j], c0[j], -(sv[j] * s0[j]));
            sv[j] = t;
        }
#pragma unroll
        for (int q = 0; q < 4; ++q) {
            llds16(bp[q], (char*)Bt + (size_t)(wid * 256 + q * 64) * 16);
            bp[q] += GSTRIDE;
        }
    }

    for (int g = 0; g < G_N; ++g) {
        __syncthreads();   // publishes buf[g&1]: A-writes + vmcnt drain of B issued last iter
        const int cur = g & 1, nxt = cur ^ 1;
        if (g + 1 < G_N) {
            // issue B(g+1) into the other buffer (drained at NEXT barrier)
#pragma unroll
            for (int q = 0; q < 4; ++q) {
                llds16(bp[q], (char*)Bt + (size_t)(nxt * 1024 + wid * 256 + q * 64) * 16);
                bp[q] += GSTRIDE;
            }
            // write A(g+1) (state k = g+2), rotate
            uint4 vc = {pack_bf2(cv[0], cv[1]), pack_bf2(cv[2], cv[3]),
                        pack_bf2(cv[4], cv[5]), pack_bf2(cv[6], cv[7])};
            *(uint4*)awc[nxt] = vc;
            uint4 vs = {pack_bf2(sv[0], sv[1]), pack_bf2(sv[2], sv[3]),
                        pack_bf2(sv[4], sv[5]), pack_bf2(sv[6], sv[7])};
            *(uint4*)aws[nxt] = vs;
#pragma unroll
            for (int j = 0; j < 8; ++j) {
                float t = __builtin_fmaf(sv[j], c0[j], cv[j] * s0[j]);
                cv[j] = __builtin_fmaf(cv[j], c0[j], -(sv[j] * s0[j]));
                sv[j] = t;
            }
        }
        // ---- fragments + 32 MFMA from buf[cur] ----
        short8 af[4], bfr[8];
#pragma unroll
        for (int t = 0; t < 4; ++t)
            af[t] = *(const short8*)&At[cur * 4096 + (lhi * 128 + wm * 64 + t * 16 + llo) * 8];
#pragma unroll
        for (int t = 0; t < 8; ++t)
            bfr[t] = *(const short8*)&Bt[cur * 8192 + (lhi * 256 + wn * 128 + t * 16 + llo) * 8];
#pragma unroll
        for (int tm = 0; tm < 4; ++tm)
#pragma unroll
            for (int tn = 0; tn < 8; ++tn)
                acc[tm][tn] = __builtin_amdgcn_mfma_f32_16x16x32_bf16(
                    af[tm], bfr[tn], acc[tm][tn], 0, 0, 0);
    }

    const int row0 = bm * BM + wm * 64 + lhi * 4;
    const int col0 = bn * BN + wn * 128 + llo;
#pragma unroll
    for (int tm = 0; tm < 4; ++tm)
#pragma unroll
        for (int tn = 0; tn < 8; ++tn)
#pragma unroll
            for (int r = 0; r < 4; ++r)
                atomicAdd(&out[(size_t)(row0 + tm * 16 + r) * J_N + col0 + tn * 16],
                          acc[tm][tn][r]);
}

// ---------------- fallback (ws too small): fp32-direct ----------------
constexpr int SPL_FB = 4;
constexpr int KS_FB = 2 * K1 / SPL_FB;
constexpr int NSTEP_FB = KS_FB / 32;

__global__ __launch_bounds__(TB)
void fkan_gemm_fb(const float* __restrict__ x,
                  const float* __restrict__ fc32,
                  float* __restrict__ out) {
    __shared__ float xs[BM][65];
    __shared__ __align__(16) ushort At[4 * 128 * 8];
    __shared__ __align__(16) ushort Bt[4 * 128 * 8];

    const int tid = threadIdx.x;
    const int bm = blockIdx.x, bn = blockIdx.y, sp = blockIdx.z;
    const int d = sp >> 1;
    const int ib = (sp & 1) << 6;
    const int rbase = ib * G_N;

    for (int idx = tid; idx < BM * 64; idx += TB) {
        int row = idx >> 6, il = idx & 63;
        xs[row][il] = x[(size_t)(bm * BM + row) * I_N + ib + il];
    }

    f32x4 acc[4][4];
#pragma unroll
    for (int a = 0; a < 4; ++a)
#pragma unroll
        for (int b = 0; b < 4; ++b) acc[a][b] = (f32x4){0.f, 0.f, 0.f, 0.f};

    const int lane = tid & 63, wid = tid >> 6;
    const int wm = wid & 1, wn = wid >> 1;
    const int lhi = lane >> 4, llo = lane & 15;
    const int am = tid & 127, akg0 = tid >> 7;

    const float* f32base = fc32 + ((size_t)d * J_N + bn * 128) * K1 + rbase;

    for (int step = 0; step < NSTEP_FB; ++step) {
        __syncthreads();
#pragma unroll
        for (int it = 0; it < 2; ++it) {
            const int kg = akg0 + it * 2;
            int r = rbase + step * 32 + kg * 8;
            int i = (int)((unsigned)r / 300u);
            int g = r - i * 300;
            float xxv = xs[am][i - ib];
            float kkf = (float)(g + 1);
            short8 avv;
#pragma unroll
            for (int j = 0; j < 8; ++j) {
                float rev = xxv * kkf * INV2PI;
                float fr = fract_(rev) + (d ? 0.0f : 0.25f);
                avv[j] = (short)f2bf(__builtin_amdgcn_sinf(fract_(fr)));
                if (j < 7) {
                    ++g; kkf += 1.0f;
                    if (g == 300) { g = 0; kkf = 1.0f; ++i; xxv = xs[am][i - ib]; }
                }
            }
            *(short8*)&At[(kg * 128 + am) * 8] = avv;
        }
#pragma unroll
        for (int it = 0; it < 2; ++it) {
            int item = tid + it * TB;
            int n = item >> 2, grp = item & 3;
            const float* gp = f32base + (size_t)n * K1 + step * 32 + grp * 8;
            float4 v0 = *(const float4*)gp;
            float4 v1 = *(const float4*)(gp + 4);
            short8 bv;
            bv[0] = (short)f2bf(v0.x); bv[1] = (short)f2bf(v0.y);
            bv[2] = (short)f2bf(v0.z); bv[3] = (short)f2bf(v0.w);
            bv[4] = (short)f2bf(v1.x); bv[5] = (short)f2bf(v1.y);
            bv[6] = (short)f2bf(v1.z); bv[7] = (short)f2bf(v1.w);
            *(short8*)&Bt[(grp * 128 + n) * 8] = bv;
        }
        __syncthreads();
        short8 af[4], bf[4];
#pragma unroll
        for (int t = 0; t < 4; ++t) {
            af[t] = *(const short8*)&At[(lhi * 128 + wm * 64 + t * 16 + llo) * 8];
            bf[t] = *(const short8*)&Bt[(lhi * 128 + wn * 64 + t * 16 + llo) * 8];
        }
#pragma unroll
        for (int tm = 0; tm < 4; ++tm)
#pragma unroll
            for (int tn = 0; tn < 4; ++tn)
                acc[tm][tn] = __builtin_amdgcn_mfma_f32_16x16x32_bf16(
                    af[tm], bf[tn], acc[tm][tn], 0, 0, 0);
    }

    const int row0 = bm * BM + wm * 64 + lhi * 4;
    const int col0 = bn * 128 + wn * 64 + llo;
#pragma unroll
    for (int tm = 0; tm < 4; ++tm)
#pragma unroll
        for (int tn = 0; tn < 4; ++tn)
#pragma unroll
            for (int r = 0; r < 4; ++r)
                atomicAdd(&out[(size_t)(row0 + tm * 16 + r) * J_N + col0 + tn * 16],
                          acc[tm][tn][r]);
}

extern "C" void kernel_launch(void* const* d_in, const int* in_sizes, int n_in,
                              void* d_out, int out_size, void* d_ws, size_t ws_size,
                              hipStream_t stream) {
    const float* x = (const float*)d_in[0];
    const float* fc = (const float*)d_in[1];
    float* out = (float*)d_out;

    hipMemsetAsync(d_out, 0, (size_t)out_size * sizeof(float), stream);

    const size_t need = (size_t)2 * J_N * K1 * sizeof(ushort);  // 78.6 MB

    if (ws_size >= need) {
        ushort* fcb = (ushort*)d_ws;
        fkan_tr<<<5 * 32 * 8, TB, 0, stream>>>(fc, fcb);         // 1280 blocks
        dim3 grid(B_N / BM, J_N / BN, NSP);                      // 32 x 2 x 8 = 512
        fkan_gemm<<<grid, TB, 0, stream>>>(x, fcb, out);
    } else {
        dim3 grid(B_N / BM, J_N / 128, SPL_FB);
        fkan_gemm_fb<<<grid, TB, 0, stream>>>(x, fc, out);
    }
}

// Round 5
// 555.343 us; speedup vs baseline: 2.1473x; 1.2563x over previous
//
#include <hip/hip_runtime.h>
#include <hip/hip_bf16.h>
#include <cstdint>

#define TB 256

typedef short short8 __attribute__((ext_vector_type(8)));
typedef float f32x4 __attribute__((ext_vector_type(4)));

constexpr int B_N = 4096, I_N = 128, J_N = 512, G_N = 300;
constexpr int K1 = I_N * G_N;            // 38400 per d
constexpr int BM = 128, BN = 256;
constexpr int NSP = 8;                   // 8 i-chunks of 16
constexpr int IC = 16;
constexpr float INV2PI = 0.15915494309189535f;

// fcb2 layout: [sp][g][kg][j][8e] bf16, kg = d*2 + ih, i = sp*16 + ih*8 + e
constexpr int GSTRIDE = 4 * 512 * 8;                // ushorts per g = 16384
constexpr size_t SPSTRIDE = (size_t)G_N * GSTRIDE;  // per sp

__device__ __forceinline__ ushort f2bf(float f) {
    unsigned int u = __float_as_uint(f);
    return (ushort)((u + 0x7FFFu + ((u >> 16) & 1u)) >> 16);
}

__device__ __forceinline__ float fract_(float x) {
#if __has_builtin(__builtin_amdgcn_fractf)
    return __builtin_amdgcn_fractf(x);
#else
    return x - floorf(x);
#endif
}

// HW packed f32x2 -> bf16x2 (RNE) — v_cvt_pk_bf16_f32 on gfx950
__device__ __forceinline__ unsigned int pack_bf2(float a, float b) {
    __hip_bfloat162 h = __float22bfloat162_rn(make_float2(a, b));
    unsigned int u;
    __builtin_memcpy(&u, &h, 4);
    return u;
}

typedef __attribute__((address_space(3))) unsigned int lds_u32_t;
typedef __attribute__((address_space(1))) const unsigned int glb_u32_t;

__device__ __forceinline__ void llds16(const void* g, void* l) {
    __builtin_amdgcn_global_load_lds(
        reinterpret_cast<glb_u32_t*>(reinterpret_cast<uintptr_t>(g)),
        reinterpret_cast<lds_u32_t*>((unsigned int)reinterpret_cast<uintptr_t>(l)),
        16, 0, 0);
}

// ---------------- pass 0: fc f32 [d][j][i][g] -> fcb2 bf16 [sp][g][kg][j][8] ----------------
// TGC=12: small tiles -> 6400 blocks -> full occupancy hides load latency
constexpr int TGC = 12;
__global__ __launch_bounds__(TB) void fkan_tr(const float* __restrict__ src,
                                              ushort* __restrict__ dst) {
    __shared__ __align__(16) ushort L[TGC * 2 * 32 * 8];   // [gl][ihl][jl][e] 12.3KB
    const int bx = blockIdx.x;
    const int sp = bx & 7, djc = (bx >> 3) & 31, gc = bx >> 8;   // gc < 25
    const int dj0 = djc * 32;
    const int d = dj0 >> 9;
    const int j0 = dj0 & 511;
    const int g0 = gc * TGC;
    const int tid = threadIdx.x;
    const int djl = tid >> 3, i2 = tid & 7;
    const int iA = sp * 16 + i2 * 2;                   // covers i = iA, iA+1
    const size_t rowA = ((size_t)(dj0 + djl) * 128 + iA) * 300;
    const int ihl = i2 >> 2;
    const int eA = (i2 & 3) * 2;

#pragma unroll
    for (int gq = 0; gq < TGC / 4; ++gq) {
        const int gg = g0 + gq * 4;
        float4 va = *(const float4*)(src + rowA + gg);          // i = iA,   4 g
        float4 vb = *(const float4*)(src + rowA + 300 + gg);    // i = iA+1, 4 g
        float a[4] = {va.x, va.y, va.z, va.w};
        float b[4] = {vb.x, vb.y, vb.z, vb.w};
#pragma unroll
        for (int t = 0; t < 4; ++t) {
            int gl = gq * 4 + t;
            unsigned int w = (unsigned int)f2bf(a[t]) | ((unsigned int)f2bf(b[t]) << 16);
            *(unsigned int*)&L[(((gl * 2 + ihl) * 32 + djl) * 8 + eA)] = w;
        }
    }
    __syncthreads();
    // write out: TGC*64 = 768 uint4 slots, contiguous 512B runs per (g, ihl)
    const uint4* Lv = (const uint4*)L;
#pragma unroll
    for (int it = 0; it < 3; ++it) {
        int s = it * 256 + tid;
        int gl = s >> 6, r = s & 63;
        int ih = r >> 5, jl = r & 31;
        size_t d16 = ((size_t)(sp * G_N + g0 + gl) * 4 + d * 2 + ih) * 512 + j0 + jl;
        ((uint4*)dst)[d16] = Lv[s];
    }
}

// ---------------- fused trig GEMM: rotation recurrence, reordered single-barrier dbuf ----------------
// split sp: i in [sp*16, +16). Per g-step BK=32: kg = d*2+ih
__global__ __launch_bounds__(TB, 2)
void fkan_gemm(const float* __restrict__ x,
               const ushort* __restrict__ fcb,
               float* __restrict__ out) {
    __shared__ __align__(16) ushort At[2 * 4 * 128 * 8];  // 16KB  [buf][kg][m][8]
    __shared__ __align__(16) ushort Bt[2 * 4 * 256 * 8];  // 32KB  [buf][kg][n][8]

    const int tid = threadIdx.x;
    const int bm = blockIdx.x, bn = blockIdx.y, sp = blockIdx.z;
    const int lane = tid & 63, wid = tid >> 6;
    const int wm = wid & 1, wn = wid >> 1;
    const int lhi = lane >> 4, llo = lane & 15;
    const int m = tid & 127, half = tid >> 7;

    // ---- init rotation state: k=1 ----
    float sv[8], cv[8], s0[8], c0[8];
    {
        const float* xr = x + ((size_t)(bm * BM + m)) * I_N + sp * IC + half * 8;
        float4 xa = *(const float4*)xr;
        float4 xb = *(const float4*)(xr + 4);
        float xv[8] = {xa.x, xa.y, xa.z, xa.w, xb.x, xb.y, xb.z, xb.w};
#pragma unroll
        for (int j = 0; j < 8; ++j) {
            float r = fract_(xv[j] * INV2PI);
            s0[j] = __builtin_amdgcn_sinf(r);
            c0[j] = __builtin_amdgcn_cosf(r);
            sv[j] = s0[j];
            cv[j] = c0[j];
        }
    }

    // ---- B pointers: wave w stages kg=w, 4 lane-linear 1KB chunks ----
    const ushort* bp[4];
#pragma unroll
    for (int q = 0; q < 4; ++q)
        bp[q] = fcb + (size_t)sp * SPSTRIDE
              + ((size_t)wid * 512 + bn * BN + q * 64 + lane) * 8;

    // LDS offsets (ushort units)
    const int aoff = (lhi * 128 + wm * 64 + llo) * 8;
    const int boff = (lhi * 256 + wn * 128 + llo) * 8;
    ushort* awc0 = &At[(half * 128 + m) * 8];        // kg = half     (cos)
    ushort* aws0 = &At[((2 + half) * 128 + m) * 8];  // kg = 2 + half (sin)

    f32x4 acc[4][8];
#pragma unroll
    for (int a = 0; a < 4; ++a)
#pragma unroll
        for (int b = 0; b < 8; ++b) acc[a][b] = (f32x4){0.f, 0.f, 0.f, 0.f};

    auto stageB = [&](int nb) {
#pragma unroll
        for (int q = 0; q < 4; ++q) {
            llds16(bp[q], (char*)Bt + (size_t)(nb * 1024 + wid * 256 + q * 64) * 16);
            bp[q] += GSTRIDE;
        }
    };
    // store current state (angle (k)x for upcoming step) then rotate by x
    auto writeA = [&](int nb) {
        uint4 vc = {pack_bf2(cv[0], cv[1]), pack_bf2(cv[2], cv[3]),
                    pack_bf2(cv[4], cv[5]), pack_bf2(cv[6], cv[7])};
        *(uint4*)(awc0 + nb * 4096) = vc;
        uint4 vs = {pack_bf2(sv[0], sv[1]), pack_bf2(sv[2], sv[3]),
                    pack_bf2(sv[4], sv[5]), pack_bf2(sv[6], sv[7])};
        *(uint4*)(aws0 + nb * 4096) = vs;
#pragma unroll
        for (int j = 0; j < 8; ++j) {
            float t = __builtin_fmaf(sv[j], c0[j], cv[j] * s0[j]);
            cv[j] = __builtin_fmaf(cv[j], c0[j], -(sv[j] * s0[j]));
            sv[j] = t;
        }
    };
    // one g-step from buffer cb; optionally stage next g into cb^1
    auto halfstep = [&](int cb, bool doNext) {
        __syncthreads();   // publishes buf cb (A-writes + vmcnt drain of its B loads)
        short8 af[4], bfr[8];
#pragma unroll
        for (int t = 0; t < 4; ++t)
            af[t] = *(const short8*)&At[cb * 4096 + aoff + t * 128];
#pragma unroll
        for (int t = 0; t < 8; ++t)
            bfr[t] = *(const short8*)&Bt[cb * 8192 + boff + t * 128];
        if (doNext) stageB(cb ^ 1);   // issued after reads: no wait on critical path
#pragma unroll
        for (int tm = 0; tm < 4; ++tm)
#pragma unroll
            for (int tn = 0; tn < 8; ++tn)
                acc[tm][tn] = __builtin_amdgcn_mfma_f32_16x16x32_bf16(
                    af[tm], bfr[tn], acc[tm][tn], 0, 0, 0);
        if (doNext) writeA(cb ^ 1);   // A-gen VALU overlaps MFMA burst
    };

    // prologue: A(0) (k=1) + B(0) into buf0
    writeA(0);
    stageB(0);

    for (int g = 0; g < G_N; g += 2) {
        halfstep(0, true);            // consume g, stage g+1 (g <= 298 so g+1 valid)
        halfstep(1, g + 2 < G_N);     // consume g+1, stage g+2 if valid
    }

    const int row0 = bm * BM + wm * 64 + lhi * 4;
    const int col0 = bn * BN + wn * 128 + llo;
#pragma unroll
    for (int tm = 0; tm < 4; ++tm)
#pragma unroll
        for (int tn = 0; tn < 8; ++tn)
#pragma unroll
            for (int r = 0; r < 4; ++r)
                atomicAdd(&out[(size_t)(row0 + tm * 16 + r) * J_N + col0 + tn * 16],
                          acc[tm][tn][r]);
}

// ---------------- fallback (ws too small): fp32-direct ----------------
constexpr int SPL_FB = 4;
constexpr int KS_FB = 2 * K1 / SPL_FB;
constexpr int NSTEP_FB = KS_FB / 32;

__global__ __launch_bounds__(TB)
void fkan_gemm_fb(const float* __restrict__ x,
                  const float* __restrict__ fc32,
                  float* __restrict__ out) {
    __shared__ float xs[BM][65];
    __shared__ __align__(16) ushort At[4 * 128 * 8];
    __shared__ __align__(16) ushort Bt[4 * 128 * 8];

    const int tid = threadIdx.x;
    const int bm = blockIdx.x, bn = blockIdx.y, sp = blockIdx.z;
    const int d = sp >> 1;
    const int ib = (sp & 1) << 6;
    const int rbase = ib * G_N;

    for (int idx = tid; idx < BM * 64; idx += TB) {
        int row = idx >> 6, il = idx & 63;
        xs[row][il] = x[(size_t)(bm * BM + row) * I_N + ib + il];
    }

    f32x4 acc[4][4];
#pragma unroll
    for (int a = 0; a < 4; ++a)
#pragma unroll
        for (int b = 0; b < 4; ++b) acc[a][b] = (f32x4){0.f, 0.f, 0.f, 0.f};

    const int lane = tid & 63, wid = tid >> 6;
    const int wm = wid & 1, wn = wid >> 1;
    const int lhi = lane >> 4, llo = lane & 15;
    const int am = tid & 127, akg0 = tid >> 7;

    const float* f32base = fc32 + ((size_t)d * J_N + bn * 128) * K1 + rbase;

    for (int step = 0; step < NSTEP_FB; ++step) {
        __syncthreads();
#pragma unroll
        for (int it = 0; it < 2; ++it) {
            const int kg = akg0 + it * 2;
            int r = rbase + step * 32 + kg * 8;
            int i = (int)((unsigned)r / 300u);
            int g = r - i * 300;
            float xxv = xs[am][i - ib];
            float kkf = (float)(g + 1);
            short8 avv;
#pragma unroll
            for (int j = 0; j < 8; ++j) {
                float rev = xxv * kkf * INV2PI;
                float fr = fract_(rev) + (d ? 0.0f : 0.25f);
                avv[j] = (short)f2bf(__builtin_amdgcn_sinf(fract_(fr)));
                if (j < 7) {
                    ++g; kkf += 1.0f;
                    if (g == 300) { g = 0; kkf = 1.0f; ++i; xxv = xs[am][i - ib]; }
                }
            }
            *(short8*)&At[(kg * 128 + am) * 8] = avv;
        }
#pragma unroll
        for (int it = 0; it < 2; ++it) {
            int item = tid + it * TB;
            int n = item >> 2, grp = item & 3;
            const float* gp = f32base + (size_t)n * K1 + step * 32 + grp * 8;
            float4 v0 = *(const float4*)gp;
            float4 v1 = *(const float4*)(gp + 4);
            short8 bv;
            bv[0] = (short)f2bf(v0.x); bv[1] = (short)f2bf(v0.y);
            bv[2] = (short)f2bf(v0.z); bv[3] = (short)f2bf(v0.w);
            bv[4] = (short)f2bf(v1.x); bv[5] = (short)f2bf(v1.y);
            bv[6] = (short)f2bf(v1.z); bv[7] = (short)f2bf(v1.w);
            *(short8*)&Bt[(grp * 128 + n) * 8] = bv;
        }
        __syncthreads();
        short8 af[4], bf[4];
#pragma unroll
        for (int t = 0; t < 4; ++t) {
            af[t] = *(const short8*)&At[(lhi * 128 + wm * 64 + t * 16 + llo) * 8];
            bf[t] = *(const short8*)&Bt[(lhi * 128 + wn * 64 + t * 16 + llo) * 8];
        }
#pragma unroll
        for (int tm = 0; tm < 4; ++tm)
#pragma unroll
            for (int tn = 0; tn < 4; ++tn)
                acc[tm][tn] = __builtin_amdgcn_mfma_f32_16x16x32_bf16(
                    af[tm], bf[tn], acc[tm][tn], 0, 0, 0);
    }

    const int row0 = bm * BM + wm * 64 + lhi * 4;
    const int col0 = bn * 128 + wn * 64 + llo;
#pragma unroll
    for (int tm = 0; tm < 4; ++tm)
#pragma unroll
        for (int tn = 0; tn < 4; ++tn)
#pragma unroll
            for (int r = 0; r < 4; ++r)
                atomicAdd(&out[(size_t)(row0 + tm * 16 + r) * J_N + col0 + tn * 16],
                          acc[tm][tn][r]);
}

extern "C" void kernel_launch(void* const* d_in, const int* in_sizes, int n_in,
                              void* d_out, int out_size, void* d_ws, size_t ws_size,
                              hipStream_t stream) {
    const float* x = (const float*)d_in[0];
    const float* fc = (const float*)d_in[1];
    float* out = (float*)d_out;

    hipMemsetAsync(d_out, 0, (size_t)out_size * sizeof(float), stream);

    const size_t need = (size_t)2 * J_N * K1 * sizeof(ushort);  // 78.6 MB

    if (ws_size >= need) {
        ushort* fcb = (ushort*)d_ws;
        fkan_tr<<<25 * 32 * 8, TB, 0, stream>>>(fc, fcb);        // 6400 blocks
        dim3 grid(B_N / BM, J_N / BN, NSP);                      // 32 x 2 x 8 = 512
        fkan_gemm<<<grid, TB, 0, stream>>>(x, fcb, out);
    } else {
        dim3 grid(B_N / BM, J_N / 128, SPL_FB);
        fkan_gemm_fb<<<grid, TB, 0, stream>>>(x, fc, out);
    }
}